// Round 14
// baseline (161.858 us; speedup 1.0000x reference)
//
#include <hip/hip_runtime.h>

typedef unsigned short u16;
typedef __attribute__((ext_vector_type(8))) __bf16 bf16x8;
typedef __attribute__((ext_vector_type(4))) float f32x4;

struct alignas(8) U16x4 { u16 x, y, z, w; };

#define MFMA16(a, b, c) __builtin_amdgcn_mfma_f32_16x16x32_bf16(a, b, c, 0, 0, 0)

__device__ __forceinline__ u16 f2bf(float f) {
    union { float f; unsigned u; } v; v.f = f;
    unsigned r = v.u + 0x7fffu + ((v.u >> 16) & 1u);
    return (u16)(r >> 16);
}

__device__ __forceinline__ float bf2f(u16 b) {
    union { unsigned u; float f; } v; v.u = (unsigned)b << 16;
    return v.f;
}

__device__ __forceinline__ unsigned cvt_pk_bf16(float lo, float hi) {
    unsigned r;
    asm("v_cvt_pk_bf16_f32 %0, %1, %2" : "=v"(r) : "v"(lo), "v"(hi));
    return r;
}

__device__ __forceinline__ float fexp2(float x) {   // raw v_exp_f32 (2^x)
    float r;
    asm("v_exp_f32 %0, %1" : "=v"(r) : "v"(x));
    return r;
}

__device__ __forceinline__ void gload_lds16(const void* g, void* l) {
    __builtin_amdgcn_global_load_lds(
        (__attribute__((address_space(1))) void*)g,
        (__attribute__((address_space(3))) void*)l, 16, 0, 0);
}

// ---------------------------------------------------------------------------
// prep: fused LN(query)+LN(context)+weight-conversion (R10 verbatim).
// NOTE: wkb and wvb MUST be allocated contiguously (Wkv = [Wk;Wv] rows 0-2047
// for gemm_kv8). Each is exactly 2MB, 256B-aligned -> contiguous.
// ---------------------------------------------------------------------------
__global__ __launch_bounds__(256)
void prep(const float* __restrict__ query, const float* __restrict__ context,
          const float* __restrict__ g_q, const float* __restrict__ b_q,
          const float* __restrict__ g_kv, const float* __restrict__ b_kv,
          u16* __restrict__ qnb, u16* __restrict__ cnb,
          const float4* __restrict__ w0, const float4* __restrict__ w1,
          const float4* __restrict__ w2, const float4* __restrict__ w3,
          U16x4* __restrict__ o0, U16x4* __restrict__ o1,
          U16x4* __restrict__ o2, U16x4* __restrict__ o3)
{
    const int blk = blockIdx.x;
    if (blk < 2560) {
        const float *x, *g, *be; u16* y16; int rb;
        if (blk < 512) { x = query;   g = g_q;  be = b_q;  y16 = qnb; rb = blk; }
        else           { x = context; g = g_kv; be = b_kv; y16 = cnb; rb = blk - 512; }
        const int wid = threadIdx.x >> 6, lane = threadIdx.x & 63;
        const size_t row = (size_t)rb * 4 + wid;
        const float4* xr = (const float4*)(x + row * 1024);
        float4 v[4];
        float s = 0.f, ss = 0.f;
#pragma unroll
        for (int i = 0; i < 4; ++i) {
            v[i] = xr[i * 64 + lane];
            s  += (v[i].x + v[i].y) + (v[i].z + v[i].w);
            ss += (v[i].x * v[i].x + v[i].y * v[i].y) + (v[i].z * v[i].z + v[i].w * v[i].w);
        }
#pragma unroll
        for (int o = 32; o; o >>= 1) { s += __shfl_xor(s, o, 64); ss += __shfl_xor(ss, o, 64); }
        const float mu = s * (1.f / 1024.f);
        const float rstd = rsqrtf(ss * (1.f / 1024.f) - mu * mu + 1e-5f);
#pragma unroll
        for (int i = 0; i < 4; ++i) {
            float4 gv = ((const float4*)g)[i * 64 + lane];
            float4 bv = ((const float4*)be)[i * 64 + lane];
            float4 o;
            o.x = (v[i].x - mu) * rstd * gv.x + bv.x;
            o.y = (v[i].y - mu) * rstd * gv.y + bv.y;
            o.z = (v[i].z - mu) * rstd * gv.z + bv.z;
            o.w = (v[i].w - mu) * rstd * gv.w + bv.w;
            U16x4 pk = { f2bf(o.x), f2bf(o.y), f2bf(o.z), f2bf(o.w) };
            ((U16x4*)(y16 + row * 1024))[i * 64 + lane] = pk;
        }
    } else {
        const int i = (blk - 2560) * 256 + threadIdx.x;
        float4 v;
        v = w0[i]; o0[i] = { f2bf(v.x), f2bf(v.y), f2bf(v.z), f2bf(v.w) };
        v = w1[i]; o1[i] = { f2bf(v.x), f2bf(v.y), f2bf(v.z), f2bf(v.w) };
        v = w2[i]; o2[i] = { f2bf(v.x), f2bf(v.y), f2bf(v.z), f2bf(v.w) };
        v = w3[i]; o3[i] = { f2bf(v.x), f2bf(v.y), f2bf(v.z), f2bf(v.w) };
    }
}

// ---------------------------------------------------------------------------
// K+V projection, 256x256 tile, counted-vmcnt 4-phase col-sweep (T3+T4+T5).
// A = cnb [8192,1024]; B = Wkv [2048,1024] ([Wk;Wv] contiguous).
// Grid 256 blocks (= 1/CU), 512 thr = 8 waves (2M x 4N), per-wave 128x64 out.
// LDS 128KB: A[2buf][2half][128][64] @0; B[2buf][4stripe][4band][16][64] @64KB.
//
// Phase p computes col-frag p (8 row-frags x 1 col x kk0,1 = 16 MFMA):
//   - A fragments (16 x b128) read once in ph0, held in regs -> A-LDS dead
//     after ph0's barrier; B-stripe p dead after phase p's barrier.
//   - Staging runs 2 tiles ahead into dead regions; all loop vmcnts COUNTED:
//     issue/phase: [ph0]=1 (B-s3 of t+1 -> buf^1), [ph1]=3 (A-h0,B-s0 of t+2
//     -> buf), [ph2]=3 (A-h1,B-s1), [ph3]=1 (B-s2).
//     Ledger (verified): data for ph0/ph1(t) staged ph1/ph2(t-2): 9 younger
//     at end-ph3(t-1) -> vmcnt(9). B-s2(t) staged ph3(t-2): 12 younger at
//     end-ph1(t) -> vmcnt(12). B-s3(t) staged ph0(t-1): 14 younger at
//     end-ph2(t) -> vmcnt(14). Prologue: tile0 full + tile1 minus B-s3 (15
//     loads), vmcnt(7). Epilogue staging clamps source (harmless re-loads)
//     so the ledger stays exact.
// Swizzle: source chunk ^= (row&7), read slot (kk*4+lg)^(lr&7) (attn-proven).
// ---------------------------------------------------------------------------
__global__ __launch_bounds__(512, 2)
void gemm_kv8(const u16* __restrict__ A, const u16* __restrict__ Wkv,
              const float* __restrict__ bkp, const float* __restrict__ bvp,
              u16* __restrict__ Kout, u16* __restrict__ Vt)
{
    __shared__ __align__(16) u16 smem[65536];   // 128 KB

    const int tid = threadIdx.x, wid = tid >> 6, lane = tid & 63;
    const int lr = lane & 15, lg = lane >> 4;
    const int rs = lr & 7;
    const int wm = wid >> 2, wn = wid & 3;

    // nt-major XCD chunking: each XCD owns one 256-col panel (B L2-resident),
    // A (16MB) streams once per XCD and hits L3 afterwards.
    const int fid = blockIdx.x;
    const int wk = (fid & 7) * 32 + (fid >> 3);
    const int nt = wk >> 5, mt = wk & 31;
    const int row0 = mt * 256, col0 = nt * 256;

    const int sr = tid >> 3;                 // staging row-in-64 (A) / row key
    const int sc = tid & 7;
    const int scol = (sc ^ (sr & 7)) * 8;    // pre-swizzled source chunk

    auto stA = [&](int buf, int h, int ko) {     // 2 loads: rows h*128 + {0,64}+sr
#pragma unroll
        for (int i = 0; i < 2; ++i)
            gload_lds16(A + (size_t)(row0 + h * 128 + i * 64 + sr) * 1024 + ko + scol,
                        (char*)smem + buf * 32768 + h * 16384 + i * 8192 + wid * 1024);
    };
    auto stB = [&](int buf, int s, int ko) {     // 1 load: stripe s (4 bands x 16 rows)
        gload_lds16(Wkv + (size_t)(col0 + (tid >> 7) * 64 + s * 16 + ((tid >> 3) & 15)) * 1024 + ko + scol,
                    (char*)smem + 65536 + buf * 32768 + s * 8192 + wid * 1024);
    };

    f32x4 acc[8][4];
#pragma unroll
    for (int m = 0; m < 8; ++m)
#pragma unroll
        for (int n = 0; n < 4; ++n) acc[m][n] = (f32x4){0.f, 0.f, 0.f, 0.f};

    // prologue: tile0 full (8 loads), tile1 minus B-s3 (7 loads)
    stA(0, 0, 0);  stA(0, 1, 0);
    stB(0, 0, 0);  stB(0, 1, 0);  stB(0, 2, 0);  stB(0, 3, 0);
    stA(1, 0, 64); stA(1, 1, 64);
    stB(1, 0, 64); stB(1, 1, 64); stB(1, 2, 64);
    asm volatile("s_waitcnt vmcnt(7)" ::: "memory");
    __builtin_amdgcn_s_barrier();

    for (int kt = 0; kt < 16; ++kt) {
        const int cur = kt & 1;
        const int ko1 = (kt < 15 ? kt + 1 : 15) * 64;   // clamped: ledger stays exact
        const int ko2 = (kt < 14 ? kt + 2 : 15) * 64;
        const u16* Ab = &smem[cur * 16384 + wm * 8192];
        const u16* Bb = &smem[32768 + cur * 16384 + wn * 1024];

        // ---- phase 0: read all A-frags + B col-frag 0; stage B-s3(t+1) ----
        bf16x8 af[8][2];
#pragma unroll
        for (int m = 0; m < 8; ++m)
#pragma unroll
            for (int kk = 0; kk < 2; ++kk)
                af[m][kk] = *(const bf16x8*)&Ab[(m * 16 + lr) * 64 + ((kk * 4 + lg) ^ rs) * 8];
        {
            bf16x8 b0 = *(const bf16x8*)&Bb[0 * 4096 + lr * 64 + (lg ^ rs) * 8];
            bf16x8 b1 = *(const bf16x8*)&Bb[0 * 4096 + lr * 64 + ((4 + lg) ^ rs) * 8];
            stB(cur ^ 1, 3, ko1);
            __builtin_amdgcn_s_setprio(1);
#pragma unroll
            for (int m = 0; m < 8; ++m) acc[m][0] = MFMA16(af[m][0], b0, acc[m][0]);
#pragma unroll
            for (int m = 0; m < 8; ++m) acc[m][0] = MFMA16(af[m][1], b1, acc[m][0]);
            __builtin_amdgcn_s_setprio(0);
        }
        __builtin_amdgcn_s_barrier();

        // ---- phase 1: B col-frag 1; stage A-h0(t+2) + B-s0(t+2) ----
        {
            bf16x8 b0 = *(const bf16x8*)&Bb[1 * 4096 + lr * 64 + (lg ^ rs) * 8];
            bf16x8 b1 = *(const bf16x8*)&Bb[1 * 4096 + lr * 64 + ((4 + lg) ^ rs) * 8];
            stA(cur, 0, ko2);
            stB(cur, 0, ko2);
            __builtin_amdgcn_s_setprio(1);
#pragma unroll
            for (int m = 0; m < 8; ++m) acc[m][1] = MFMA16(af[m][0], b0, acc[m][1]);
#pragma unroll
            for (int m = 0; m < 8; ++m) acc[m][1] = MFMA16(af[m][1], b1, acc[m][1]);
            __builtin_amdgcn_s_setprio(0);
        }
        asm volatile("s_waitcnt vmcnt(12)" ::: "memory");
        __builtin_amdgcn_s_barrier();

        // ---- phase 2: B col-frag 2; stage A-h1(t+2) + B-s1(t+2) ----
        {
            bf16x8 b0 = *(const bf16x8*)&Bb[2 * 4096 + lr * 64 + (lg ^ rs) * 8];
            bf16x8 b1 = *(const bf16x8*)&Bb[2 * 4096 + lr * 64 + ((4 + lg) ^ rs) * 8];
            stA(cur, 1, ko2);
            stB(cur, 1, ko2);
            __builtin_amdgcn_s_setprio(1);
#pragma unroll
            for (int m = 0; m < 8; ++m) acc[m][2] = MFMA16(af[m][0], b0, acc[m][2]);
#pragma unroll
            for (int m = 0; m < 8; ++m) acc[m][2] = MFMA16(af[m][1], b1, acc[m][2]);
            __builtin_amdgcn_s_setprio(0);
        }
        asm volatile("s_waitcnt vmcnt(14)" ::: "memory");
        __builtin_amdgcn_s_barrier();

        // ---- phase 3: B col-frag 3; stage B-s2(t+2) ----
        {
            bf16x8 b0 = *(const bf16x8*)&Bb[3 * 4096 + lr * 64 + (lg ^ rs) * 8];
            bf16x8 b1 = *(const bf16x8*)&Bb[3 * 4096 + lr * 64 + ((4 + lg) ^ rs) * 8];
            stB(cur, 2, ko2);
            __builtin_amdgcn_s_setprio(1);
#pragma unroll
            for (int m = 0; m < 8; ++m) acc[m][3] = MFMA16(af[m][0], b0, acc[m][3]);
#pragma unroll
            for (int m = 0; m < 8; ++m) acc[m][3] = MFMA16(af[m][1], b1, acc[m][3]);
            __builtin_amdgcn_s_setprio(0);
        }
        asm volatile("s_waitcnt vmcnt(9)" ::: "memory");
        __builtin_amdgcn_s_barrier();
    }
    asm volatile("s_waitcnt vmcnt(0)" ::: "memory");

    // epilogue: nt<4 -> K row-major; nt>=4 -> V^T scatter (as R10)
    const bool is_v = (nt >= 4);
#pragma unroll
    for (int m = 0; m < 8; ++m) {
#pragma unroll
        for (int n = 0; n < 4; ++n) {
            const int r = row0 + wm * 128 + m * 16 + lg * 4;
            const int ncol = col0 + wn * 64 + n * 16 + lr;
            if (!is_v) {
                const float kb = bkp[ncol];
#pragma unroll
                for (int j = 0; j < 4; ++j)
                    Kout[(size_t)(r + j) * 1024 + ncol] = f2bf(acc[m][n][j] + kb);
            } else {
                const int vc = ncol - 1024;
                const float vb = bvp[vc];
                const size_t base = ((size_t)(r >> 12) * 1024 + vc) * 4096 + (r & 4095);
                U16x4 pk = { f2bf(acc[m][n][0] + vb), f2bf(acc[m][n][1] + vb),
                             f2bf(acc[m][n][2] + vb), f2bf(acc[m][n][3] + vb) };
                *(U16x4*)&Vt[base] = pk;
            }
        }
    }
}

// ---------------------------------------------------------------------------
// Q/O projection GEMM, 64x128 tile (R10 verbatim).
// MODE 0: bf16 out * alpha. MODE 1: f32 out + bf16 residual.
// ---------------------------------------------------------------------------
template<int MODE>
__global__ __launch_bounds__(256)
void gemm_bt64(const u16* __restrict__ A, const u16* __restrict__ W,
               const float* __restrict__ bias, const u16* __restrict__ resid,
               void* __restrict__ Cp, int M, int N, int K, float alpha)
{
    constexpr int BK = 64;
    __shared__ __align__(16) u16 sA[64 * BK];
    __shared__ __align__(16) u16 sB[128 * BK];
    const int tid = threadIdx.x, wid = tid >> 6, lane = tid & 63;
    const int lr = lane & 15, lg = lane >> 4;
    const int wr = wid >> 1, wc = wid & 1;
    const int row0 = blockIdx.x * 64, col0 = blockIdx.y * 128;
    const int srow = wid * 8 + (lane >> 3), scol = (lane & 7) * 8;

    const u16* Ag = A + (size_t)(row0 + srow) * K + scol;
    const u16* Wg = W + (size_t)(col0 + srow) * K + scol;

    f32x4 acc[2][4];
#pragma unroll
    for (int m = 0; m < 2; ++m)
#pragma unroll
        for (int n = 0; n < 4; ++n) acc[m][n] = (f32x4){0.f, 0.f, 0.f, 0.f};

    for (int k0 = 0; k0 < K; k0 += BK) {
        __syncthreads();
#pragma unroll
        for (int i = 0; i < 2; ++i)
            gload_lds16(Ag + (size_t)i * 32 * K + k0, (char*)sA + i * 4096 + wid * 1024);
#pragma unroll
        for (int i = 0; i < 4; ++i)
            gload_lds16(Wg + (size_t)i * 32 * K + k0, (char*)sB + i * 4096 + wid * 1024);
        __syncthreads();
#pragma unroll
        for (int kk = 0; kk < 2; ++kk) {
            bf16x8 af[2], bfr[4];
#pragma unroll
            for (int m = 0; m < 2; ++m)
                af[m] = *(const bf16x8*)&sA[(wr * 32 + m * 16 + lr) * BK + kk * 32 + lg * 8];
#pragma unroll
            for (int n = 0; n < 4; ++n)
                bfr[n] = *(const bf16x8*)&sB[(wc * 64 + n * 16 + lr) * BK + kk * 32 + lg * 8];
#pragma unroll
            for (int m = 0; m < 2; ++m)
#pragma unroll
                for (int n = 0; n < 4; ++n)
                    acc[m][n] = MFMA16(af[m], bfr[n], acc[m][n]);
        }
    }

#pragma unroll
    for (int m = 0; m < 2; ++m) {
#pragma unroll
        for (int n = 0; n < 4; ++n) {
            const int r = row0 + wr * 32 + m * 16 + lg * 4;
            const int c = col0 + wc * 64 + n * 16 + lr;
            const float bv = bias[c];
            if constexpr (MODE == 0) {
                u16* C = (u16*)Cp;
#pragma unroll
                for (int j = 0; j < 4; ++j)
                    C[(size_t)(r + j) * N + c] = f2bf((acc[m][n][j] + bv) * alpha);
            } else {
                float* C = (float*)Cp;
#pragma unroll
                for (int j = 0; j < 4; ++j)
                    C[(size_t)(r + j) * N + c] =
                        (acc[m][n][j] + bv) + bf2f(resid[(size_t)(r + j) * N + c]);
            }
        }
    }
}

// ---------------------------------------------------------------------------
// Flash cross-attention, v3 verbatim (best measured: 65.5 us).
// ---------------------------------------------------------------------------
__global__ __launch_bounds__(512, 4)
void attn_fwd(const u16* __restrict__ Q, const u16* __restrict__ Kg,
              const u16* __restrict__ Vt, u16* __restrict__ O)
{
    constexpr int D = 1024, CSTR = 19;
    __shared__ __align__(16) char smem[81920];   // K 32K | V 32K | P 16K

    const int tid = threadIdx.x, wid = tid >> 6, lane = tid & 63;
    const int grp = wid >> 2, w = wid & 3;
    const int lr = lane & 15, lg = lane >> 4;
    const int rs = lr & 7;
    const int pkey = (lr & 7) << 4;

    const int fid = blockIdx.x;
    const int wk = (fid & 7) * 64 + (fid >> 3);
    const int qblk = wk & 15, h = (wk >> 4) & 15, b = wk >> 8;
    const int q0 = qblk * 64 + w * 16;

    const u16* Qrow = Q + (size_t)(b * 1024 + q0 + lr) * D + h * 64;
    const bf16x8 qf0 = *(const bf16x8*)(Qrow + lg * 8);
    const bf16x8 qf1 = *(const bf16x8*)(Qrow + 32 + lg * 8);

    const int srow = w * 8 + (lane >> 3);
    const int scol = ((lane & 7) ^ (srow & 7)) * 8;
    const u16* kp = Kg + (size_t)(b * 4096 + grp * 2048 + srow) * D + h * 64 + scol;
    const u16* vp = Vt + ((size_t)(b * 16 + h) * 64 + srow) * 4096 + grp * 2048 + scol;

    char* sProw = smem + 65536 + wid * 2048 + lr * 128;

    f32x4 po[4];
#pragma unroll
    for (int df = 0; df < 4; ++df) po[df] = (f32x4){0.f, 0.f, 0.f, 0.f};
    float m = -INFINITY, l = 0.f;

    {
        char* kd = smem + grp * 8192 + w * 1024;
        char* vd = smem + 32768 + grp * 8192 + w * 1024;
        gload_lds16(kp,                      kd);
        gload_lds16(kp + (size_t)32 * D,     kd + 4096);
        gload_lds16(vp,                      vd);
        gload_lds16(vp + (size_t)32 * 4096,  vd + 4096);
        kp += (size_t)64 * D; vp += 64;
    }
    asm volatile("s_waitcnt vmcnt(0)" ::: "memory");
    asm volatile("s_barrier" ::: "memory");

    for (int t = 0; t < 32; ++t) {
        const int cur = t & 1;
        if (t < 31) {
            char* kd = smem + (cur ^ 1) * 16384 + grp * 8192 + w * 1024;
            char* vd = smem + 32768 + (cur ^ 1) * 16384 + grp * 8192 + w * 1024;
            gload_lds16(kp,                      kd);
            gload_lds16(kp + (size_t)32 * D,     kd + 4096);
            gload_lds16(vp,                      vd);
            gload_lds16(vp + (size_t)32 * 4096,  vd + 4096);
            kp += (size_t)64 * D; vp += 64;
        }

        const u16* kb = (const u16*)(smem + cur * 16384 + grp * 8192);
        const u16* vb = (const u16*)(smem + 32768 + cur * 16384 + grp * 8192);

        f32x4 s4[4];
#pragma unroll
        for (int f = 0; f < 4; ++f) {
            const int r = f * 16 + lr;
            bf16x8 k0v = *(const bf16x8*)&kb[r * 64 + (lg ^ rs) * 8];
            bf16x8 k1v = *(const bf16x8*)&kb[r * 64 + ((lg + 4) ^ rs) * 8];
            f32x4 z = (f32x4){0.f, 0.f, 0.f, 0.f};
            z = MFMA16(k0v, qf0, z);
            s4[f] = MFMA16(k1v, qf1, z);
        }

        float pmax = fmaxf(fmaxf(fmaxf(s4[0][0], s4[0][1]), fmaxf(s4[0][2], s4[0][3])),
                     fmaxf(fmaxf(fmaxf(s4[1][0], s4[1][1]), fmaxf(s4[1][2], s4[1][3])),
                     fmaxf(fmaxf(fmaxf(s4[2][0], s4[2][1]), fmaxf(s4[2][2], s4[2][3])),
                           fmaxf(fmaxf(s4[3][0], s4[3][1]), fmaxf(s4[3][2], s4[3][3])))));
        if (!__all(pmax <= m)) {
            float tmax = fmaxf(pmax, __shfl_xor(pmax, 16, 64));
            tmax = fmaxf(tmax, __shfl_xor(tmax, 32, 64));
            const float mn = fmaxf(m, tmax);
            const float corr = fexp2(m - mn);
            l *= corr;
#pragma unroll
            for (int df = 0; df < 4; ++df) po[df] *= corr;
            m = mn;
        }
        float lsum = 0.f;
        uint2 pk[4];
#pragma unroll
        for (int f = 0; f < 4; ++f) {
            float p0 = fexp2(s4[f][0] - m);
            float p1 = fexp2(s4[f][1] - m);
            float p2 = fexp2(s4[f][2] - m);
            float p3 = fexp2(s4[f][3] - m);
            lsum += (p0 + p1) + (p2 + p3);
            pk[f].x = cvt_pk_bf16(p0, p1);
            pk[f].y = cvt_pk_bf16(p2, p3);
        }
        l += lsum;

#pragma unroll
        for (int f = 0; f < 4; ++f)
            *(uint2*)(sProw + ((f * 32 + lg * 8) ^ pkey)) = pk[f];

#pragma unroll
        for (int c = 0; c < 2; ++c) {
            bf16x8 pf = *(const bf16x8*)(sProw + ((c * 64 + lg * 16) ^ pkey));
#pragma unroll
            for (int df = 0; df < 4; ++df) {
                const int r = df * 16 + lr;
                bf16x8 vf = *(const bf16x8*)&vb[r * 64 + ((c * 4 + lg) ^ rs) * 8];
                po[df] = MFMA16(vf, pf, po[df]);
            }
        }

        asm volatile("s_waitcnt vmcnt(0)" ::: "memory");
        asm volatile("s_barrier" ::: "memory");
    }

    l += __shfl_xor(l, 16, 64);
    l += __shfl_xor(l, 32, 64);

    float* cb = (float*)smem;
    if (grp == 1) {
        float* dst = cb + (size_t)(w * 64 + lane) * CSTR;
        dst[0] = m; dst[1] = l;
#pragma unroll
        for (int df = 0; df < 4; ++df)
#pragma unroll
            for (int j = 0; j < 4; ++j) dst[2 + df * 4 + j] = po[df][j];
    }
    __syncthreads();
    if (grp == 0) {
        const float* src = cb + (size_t)(w * 64 + lane) * CSTR;
        const float m1 = src[0], l1 = src[1];
        const float M = fmaxf(m, m1);
        const float c0 = fexp2(m - M), c1 = fexp2(m1 - M);
        const float rl = 1.f / (l * c0 + l1 * c1);
        u16* Orow = O + (size_t)(b * 1024 + q0 + lr) * D + h * 64;
#pragma unroll
        for (int df = 0; df < 4; ++df) {
            U16x4 opk = { f2bf((po[df][0] * c0 + src[2 + df * 4 + 0] * c1) * rl),
                          f2bf((po[df][1] * c0 + src[2 + df * 4 + 1] * c1) * rl),
                          f2bf((po[df][2] * c0 + src[2 + df * 4 + 2] * c1) * rl),
                          f2bf((po[df][3] * c0 + src[2 + df * 4 + 3] * c1) * rl) };
            *(U16x4*)&Orow[df * 16 + lg * 4] = opk;
        }
    }
}

// ---------------------------------------------------------------------------
extern "C" void kernel_launch(void* const* d_in, const int* in_sizes, int n_in,
                              void* d_out, int out_size, void* d_ws, size_t ws_size,
                              hipStream_t stream)
{
    const float* query   = (const float*)d_in[0];
    const float* context = (const float*)d_in[1];
    const float* wq = (const float*)d_in[2];
    const float* bq = (const float*)d_in[3];
    const float* wk = (const float*)d_in[4];
    const float* bk = (const float*)d_in[5];
    const float* wv = (const float*)d_in[6];
    const float* bv = (const float*)d_in[7];
    const float* wo = (const float*)d_in[8];
    const float* bo = (const float*)d_in[9];
    const float* g_q  = (const float*)d_in[10];
    const float* b_q  = (const float*)d_in[11];
    const float* g_kv = (const float*)d_in[12];
    const float* b_kv = (const float*)d_in[13];

    char* p = (char*)d_ws;
    auto alloc = [&](size_t bytes) { char* r = p; p += (bytes + 255) & ~(size_t)255; return r; };
    u16*   wqb  = (u16*)alloc(1024 * 1024 * 2);
    u16*   wkb  = (u16*)alloc(1024 * 1024 * 2);   // wkb+wvb contiguous = Wkv [2048,1024]
    u16*   wvb  = (u16*)alloc(1024 * 1024 * 2);
    u16*   wob  = (u16*)alloc(1024 * 1024 * 2);
    u16*   qnb  = (u16*)alloc((size_t)2048 * 1024 * 2);
    u16*   cnb  = (u16*)alloc((size_t)8192 * 1024 * 2);
    u16*   Qb   = (u16*)alloc((size_t)2048 * 1024 * 2);
    u16*   Kb   = (u16*)alloc((size_t)8192 * 1024 * 2);
    u16*   Vtb  = (u16*)alloc((size_t)8192 * 1024 * 2);
    u16*   AOb  = (u16*)alloc((size_t)2048 * 1024 * 2);

    prep<<<3584, 256, 0, stream>>>(query, context, g_q, b_q, g_kv, b_kv,
                                   qnb, cnb,
                                   (const float4*)wq, (const float4*)wk,
                                   (const float4*)wv, (const float4*)wo,
                                   (U16x4*)wqb, (U16x4*)wkb, (U16x4*)wvb, (U16x4*)wob);

    // Q = (qn.wq^T + bq) * 0.125 * log2(e)  (attn scale + exp2 conversion folded)
    gemm_bt64<0><<<dim3(32, 8), 256, 0, stream>>>(qnb, wqb, bq, nullptr, Qb, 2048, 1024, 1024, 0.18033688f);
    // K row-major + V transposed, one pass over cnb — 256x256 counted-vmcnt kernel
    gemm_kv8<<<dim3(256), 512, 0, stream>>>(cnb, wkb, bk, bv, Kb, Vtb);

    attn_fwd<<<dim3(512), 512, 0, stream>>>(Qb, Kb, Vtb, AOb);

    // out = qn(bf16) + AO.wo^T + bo   (f32 output, residual fused)
    gemm_bt64<1><<<dim3(32, 8), 256, 0, stream>>>(AOb, wob, bo, qnb, d_out, 2048, 1024, 1024, 1.0f);
}

// Round 15
// 155.802 us; speedup vs baseline: 1.0389x; 1.0389x over previous
//
#include <hip/hip_runtime.h>

typedef unsigned short u16;
typedef __attribute__((ext_vector_type(8))) __bf16 bf16x8;
typedef __attribute__((ext_vector_type(4))) float f32x4;
typedef __attribute__((ext_vector_type(16))) float f32x16;
typedef __attribute__((ext_vector_type(2))) int i32x2;

struct alignas(8) U16x4 { u16 x, y, z, w; };

#define MFMA16(a, b, c) __builtin_amdgcn_mfma_f32_16x16x32_bf16(a, b, c, 0, 0, 0)
#define MFMA32(a, b, c) __builtin_amdgcn_mfma_f32_32x32x16_bf16(a, b, c, 0, 0, 0)

__device__ __forceinline__ u16 f2bf(float f) {
    union { float f; unsigned u; } v; v.f = f;
    unsigned r = v.u + 0x7fffu + ((v.u >> 16) & 1u);
    return (u16)(r >> 16);
}

__device__ __forceinline__ float bf2f(u16 b) {
    union { unsigned u; float f; } v; v.u = (unsigned)b << 16;
    return v.f;
}

__device__ __forceinline__ unsigned cvt_pk_bf16(float lo, float hi) {
    unsigned r;
    asm("v_cvt_pk_bf16_f32 %0, %1, %2" : "=v"(r) : "v"(lo), "v"(hi));
    return r;
}

__device__ __forceinline__ float fexp2(float x) {   // raw v_exp_f32 (2^x)
    float r;
    asm("v_exp_f32 %0, %1" : "=v"(r) : "v"(x));
    return r;
}

__device__ __forceinline__ void gload_lds16(const void* g, void* l) {
    __builtin_amdgcn_global_load_lds(
        (__attribute__((address_space(1))) void*)g,
        (__attribute__((address_space(3))) void*)l, 16, 0, 0);
}

// ---------------------------------------------------------------------------
// prep: fused LN(query)+LN(context)+weight-conversion (R10 verbatim).
// wkb/wvb contiguous (Wkv for gemm_kv8).
// ---------------------------------------------------------------------------
__global__ __launch_bounds__(256)
void prep(const float* __restrict__ query, const float* __restrict__ context,
          const float* __restrict__ g_q, const float* __restrict__ b_q,
          const float* __restrict__ g_kv, const float* __restrict__ b_kv,
          u16* __restrict__ qnb, u16* __restrict__ cnb,
          const float4* __restrict__ w0, const float4* __restrict__ w1,
          const float4* __restrict__ w2, const float4* __restrict__ w3,
          U16x4* __restrict__ o0, U16x4* __restrict__ o1,
          U16x4* __restrict__ o2, U16x4* __restrict__ o3)
{
    const int blk = blockIdx.x;
    if (blk < 2560) {
        const float *x, *g, *be; u16* y16; int rb;
        if (blk < 512) { x = query;   g = g_q;  be = b_q;  y16 = qnb; rb = blk; }
        else           { x = context; g = g_kv; be = b_kv; y16 = cnb; rb = blk - 512; }
        const int wid = threadIdx.x >> 6, lane = threadIdx.x & 63;
        const size_t row = (size_t)rb * 4 + wid;
        const float4* xr = (const float4*)(x + row * 1024);
        float4 v[4];
        float s = 0.f, ss = 0.f;
#pragma unroll
        for (int i = 0; i < 4; ++i) {
            v[i] = xr[i * 64 + lane];
            s  += (v[i].x + v[i].y) + (v[i].z + v[i].w);
            ss += (v[i].x * v[i].x + v[i].y * v[i].y) + (v[i].z * v[i].z + v[i].w * v[i].w);
        }
#pragma unroll
        for (int o = 32; o; o >>= 1) { s += __shfl_xor(s, o, 64); ss += __shfl_xor(ss, o, 64); }
        const float mu = s * (1.f / 1024.f);
        const float rstd = rsqrtf(ss * (1.f / 1024.f) - mu * mu + 1e-5f);
#pragma unroll
        for (int i = 0; i < 4; ++i) {
            float4 gv = ((const float4*)g)[i * 64 + lane];
            float4 bv = ((const float4*)be)[i * 64 + lane];
            float4 o;
            o.x = (v[i].x - mu) * rstd * gv.x + bv.x;
            o.y = (v[i].y - mu) * rstd * gv.y + bv.y;
            o.z = (v[i].z - mu) * rstd * gv.z + bv.z;
            o.w = (v[i].w - mu) * rstd * gv.w + bv.w;
            U16x4 pk = { f2bf(o.x), f2bf(o.y), f2bf(o.z), f2bf(o.w) };
            ((U16x4*)(y16 + row * 1024))[i * 64 + lane] = pk;
        }
    } else {
        const int i = (blk - 2560) * 256 + threadIdx.x;
        float4 v;
        v = w0[i]; o0[i] = { f2bf(v.x), f2bf(v.y), f2bf(v.z), f2bf(v.w) };
        v = w1[i]; o1[i] = { f2bf(v.x), f2bf(v.y), f2bf(v.z), f2bf(v.w) };
        v = w2[i]; o2[i] = { f2bf(v.x), f2bf(v.y), f2bf(v.z), f2bf(v.w) };
        v = w3[i]; o3[i] = { f2bf(v.x), f2bf(v.y), f2bf(v.z), f2bf(v.w) };
    }
}

// ---------------------------------------------------------------------------
// K+V projection, 256x256 counted-vmcnt 4-phase (R11/R14 verbatim, neutral
// vs 128-2ph but kept: same speed, fewer blocks).
// ---------------------------------------------------------------------------
__global__ __launch_bounds__(512, 2)
void gemm_kv8(const u16* __restrict__ A, const u16* __restrict__ Wkv,
              const float* __restrict__ bkp, const float* __restrict__ bvp,
              u16* __restrict__ Kout, u16* __restrict__ Vt)
{
    __shared__ __align__(16) u16 smem[65536];   // 128 KB

    const int tid = threadIdx.x, wid = tid >> 6, lane = tid & 63;
    const int lr = lane & 15, lg = lane >> 4;
    const int rs = lr & 7;
    const int wm = wid >> 2, wn = wid & 3;

    const int fid = blockIdx.x;
    const int wk = (fid & 7) * 32 + (fid >> 3);
    const int nt = wk >> 5, mt = wk & 31;
    const int row0 = mt * 256, col0 = nt * 256;

    const int sr = tid >> 3;
    const int sc = tid & 7;
    const int scol = (sc ^ (sr & 7)) * 8;

    auto stA = [&](int buf, int h, int ko) {
#pragma unroll
        for (int i = 0; i < 2; ++i)
            gload_lds16(A + (size_t)(row0 + h * 128 + i * 64 + sr) * 1024 + ko + scol,
                        (char*)smem + buf * 32768 + h * 16384 + i * 8192 + wid * 1024);
    };
    auto stB = [&](int buf, int s, int ko) {
        gload_lds16(Wkv + (size_t)(col0 + (tid >> 7) * 64 + s * 16 + ((tid >> 3) & 15)) * 1024 + ko + scol,
                    (char*)smem + 65536 + buf * 32768 + s * 8192 + wid * 1024);
    };

    f32x4 acc[8][4];
#pragma unroll
    for (int m = 0; m < 8; ++m)
#pragma unroll
        for (int n = 0; n < 4; ++n) acc[m][n] = (f32x4){0.f, 0.f, 0.f, 0.f};

    stA(0, 0, 0);  stA(0, 1, 0);
    stB(0, 0, 0);  stB(0, 1, 0);  stB(0, 2, 0);  stB(0, 3, 0);
    stA(1, 0, 64); stA(1, 1, 64);
    stB(1, 0, 64); stB(1, 1, 64); stB(1, 2, 64);
    asm volatile("s_waitcnt vmcnt(7)" ::: "memory");
    __builtin_amdgcn_s_barrier();

    for (int kt = 0; kt < 16; ++kt) {
        const int cur = kt & 1;
        const int ko1 = (kt < 15 ? kt + 1 : 15) * 64;
        const int ko2 = (kt < 14 ? kt + 2 : 15) * 64;
        const u16* Ab = &smem[cur * 16384 + wm * 8192];
        const u16* Bb = &smem[32768 + cur * 16384 + wn * 1024];

        bf16x8 af[8][2];
#pragma unroll
        for (int m = 0; m < 8; ++m)
#pragma unroll
            for (int kk = 0; kk < 2; ++kk)
                af[m][kk] = *(const bf16x8*)&Ab[(m * 16 + lr) * 64 + ((kk * 4 + lg) ^ rs) * 8];
        {
            bf16x8 b0 = *(const bf16x8*)&Bb[0 * 4096 + lr * 64 + (lg ^ rs) * 8];
            bf16x8 b1 = *(const bf16x8*)&Bb[0 * 4096 + lr * 64 + ((4 + lg) ^ rs) * 8];
            stB(cur ^ 1, 3, ko1);
            __builtin_amdgcn_s_setprio(1);
#pragma unroll
            for (int m = 0; m < 8; ++m) acc[m][0] = MFMA16(af[m][0], b0, acc[m][0]);
#pragma unroll
            for (int m = 0; m < 8; ++m) acc[m][0] = MFMA16(af[m][1], b1, acc[m][0]);
            __builtin_amdgcn_s_setprio(0);
        }
        __builtin_amdgcn_s_barrier();

        {
            bf16x8 b0 = *(const bf16x8*)&Bb[1 * 4096 + lr * 64 + (lg ^ rs) * 8];
            bf16x8 b1 = *(const bf16x8*)&Bb[1 * 4096 + lr * 64 + ((4 + lg) ^ rs) * 8];
            stA(cur, 0, ko2);
            stB(cur, 0, ko2);
            __builtin_amdgcn_s_setprio(1);
#pragma unroll
            for (int m = 0; m < 8; ++m) acc[m][1] = MFMA16(af[m][0], b0, acc[m][1]);
#pragma unroll
            for (int m = 0; m < 8; ++m) acc[m][1] = MFMA16(af[m][1], b1, acc[m][1]);
            __builtin_amdgcn_s_setprio(0);
        }
        asm volatile("s_waitcnt vmcnt(12)" ::: "memory");
        __builtin_amdgcn_s_barrier();

        {
            bf16x8 b0 = *(const bf16x8*)&Bb[2 * 4096 + lr * 64 + (lg ^ rs) * 8];
            bf16x8 b1 = *(const bf16x8*)&Bb[2 * 4096 + lr * 64 + ((4 + lg) ^ rs) * 8];
            stA(cur, 1, ko2);
            stB(cur, 1, ko2);
            __builtin_amdgcn_s_setprio(1);
#pragma unroll
            for (int m = 0; m < 8; ++m) acc[m][2] = MFMA16(af[m][0], b0, acc[m][2]);
#pragma unroll
            for (int m = 0; m < 8; ++m) acc[m][2] = MFMA16(af[m][1], b1, acc[m][2]);
            __builtin_amdgcn_s_setprio(0);
        }
        asm volatile("s_waitcnt vmcnt(14)" ::: "memory");
        __builtin_amdgcn_s_barrier();

        {
            bf16x8 b0 = *(const bf16x8*)&Bb[3 * 4096 + lr * 64 + (lg ^ rs) * 8];
            bf16x8 b1 = *(const bf16x8*)&Bb[3 * 4096 + lr * 64 + ((4 + lg) ^ rs) * 8];
            stB(cur, 2, ko2);
            __builtin_amdgcn_s_setprio(1);
#pragma unroll
            for (int m = 0; m < 8; ++m) acc[m][3] = MFMA16(af[m][0], b0, acc[m][3]);
#pragma unroll
            for (int m = 0; m < 8; ++m) acc[m][3] = MFMA16(af[m][1], b1, acc[m][3]);
            __builtin_amdgcn_s_setprio(0);
        }
        asm volatile("s_waitcnt vmcnt(9)" ::: "memory");
        __builtin_amdgcn_s_barrier();
    }
    asm volatile("s_waitcnt vmcnt(0)" ::: "memory");

    const bool is_v = (nt >= 4);
#pragma unroll
    for (int m = 0; m < 8; ++m) {
#pragma unroll
        for (int n = 0; n < 4; ++n) {
            const int r = row0 + wm * 128 + m * 16 + lg * 4;
            const int ncol = col0 + wn * 64 + n * 16 + lr;
            if (!is_v) {
                const float kb = bkp[ncol];
#pragma unroll
                for (int j = 0; j < 4; ++j)
                    Kout[(size_t)(r + j) * 1024 + ncol] = f2bf(acc[m][n][j] + kb);
            } else {
                const int vc = ncol - 1024;
                const float vb = bvp[vc];
                const size_t base = ((size_t)(r >> 12) * 1024 + vc) * 4096 + (r & 4095);
                U16x4 pk = { f2bf(acc[m][n][0] + vb), f2bf(acc[m][n][1] + vb),
                             f2bf(acc[m][n][2] + vb), f2bf(acc[m][n][3] + vb) };
                *(U16x4*)&Vt[base] = pk;
            }
        }
    }
}

// ---------------------------------------------------------------------------
// Q/O projection GEMM, 64x128 tile (R10 verbatim).
// ---------------------------------------------------------------------------
template<int MODE>
__global__ __launch_bounds__(256)
void gemm_bt64(const u16* __restrict__ A, const u16* __restrict__ W,
               const float* __restrict__ bias, const u16* __restrict__ resid,
               void* __restrict__ Cp, int M, int N, int K, float alpha)
{
    constexpr int BK = 64;
    __shared__ __align__(16) u16 sA[64 * BK];
    __shared__ __align__(16) u16 sB[128 * BK];
    const int tid = threadIdx.x, wid = tid >> 6, lane = tid & 63;
    const int lr = lane & 15, lg = lane >> 4;
    const int wr = wid >> 1, wc = wid & 1;
    const int row0 = blockIdx.x * 64, col0 = blockIdx.y * 128;
    const int srow = wid * 8 + (lane >> 3), scol = (lane & 7) * 8;

    const u16* Ag = A + (size_t)(row0 + srow) * K + scol;
    const u16* Wg = W + (size_t)(col0 + srow) * K + scol;

    f32x4 acc[2][4];
#pragma unroll
    for (int m = 0; m < 2; ++m)
#pragma unroll
        for (int n = 0; n < 4; ++n) acc[m][n] = (f32x4){0.f, 0.f, 0.f, 0.f};

    for (int k0 = 0; k0 < K; k0 += BK) {
        __syncthreads();
#pragma unroll
        for (int i = 0; i < 2; ++i)
            gload_lds16(Ag + (size_t)i * 32 * K + k0, (char*)sA + i * 4096 + wid * 1024);
#pragma unroll
        for (int i = 0; i < 4; ++i)
            gload_lds16(Wg + (size_t)i * 32 * K + k0, (char*)sB + i * 4096 + wid * 1024);
        __syncthreads();
#pragma unroll
        for (int kk = 0; kk < 2; ++kk) {
            bf16x8 af[2], bfr[4];
#pragma unroll
            for (int m = 0; m < 2; ++m)
                af[m] = *(const bf16x8*)&sA[(wr * 32 + m * 16 + lr) * BK + kk * 32 + lg * 8];
#pragma unroll
            for (int n = 0; n < 4; ++n)
                bfr[n] = *(const bf16x8*)&sB[(wc * 64 + n * 16 + lr) * BK + kk * 32 + lg * 8];
#pragma unroll
            for (int m = 0; m < 2; ++m)
#pragma unroll
                for (int n = 0; n < 4; ++n)
                    acc[m][n] = MFMA16(af[m], bfr[n], acc[m][n]);
        }
    }

#pragma unroll
    for (int m = 0; m < 2; ++m) {
#pragma unroll
        for (int n = 0; n < 4; ++n) {
            const int r = row0 + wr * 32 + m * 16 + lg * 4;
            const int c = col0 + wc * 64 + n * 16 + lr;
            const float bv = bias[c];
            if constexpr (MODE == 0) {
                u16* C = (u16*)Cp;
#pragma unroll
                for (int j = 0; j < 4; ++j)
                    C[(size_t)(r + j) * N + c] = f2bf((acc[m][n][j] + bv) * alpha);
            } else {
                float* C = (float*)Cp;
#pragma unroll
                for (int j = 0; j < 4; ++j)
                    C[(size_t)(r + j) * N + c] =
                        (acc[m][n][j] + bv) + bf2f(resid[(size_t)(r + j) * N + c]);
            }
        }
    }
}

// ---------------------------------------------------------------------------
// Flash cross-attention v7: 32x32 MFMA, swapped QK^T, ZERO-LDS softmax.
//   4 waves/block (256 thr): grp = wid>>1 (kv half), w = wid&1 (32-q block).
//   Per wave: 32 q-rows. Q held in regs (4x bf16x8). Per 64-kv tile:
//     S^T[kv][q] = mfma32(Kfrag, Qfrag): C col=lane&31=q, row=kv via
//     (reg&3)+8*(reg>>2)+4*(lane>>5) -> softmax per-lane + 1 shfl_xor(32).
//     P -> PV A-operand IN REGISTERS: 16 cvt_pk + 8 permlane32_swap (T12;
//     "one swap fills two output words" — derivation verified for all h/kq).
//     out^T[d][q] = mfma32(V^Tfrag, Pfrag) -> O col=q matches softmax lane
//     mapping so rescale/normalize stay per-lane.
//   K/V^T LDS tiles chunk-XOR swizzled (v3-proven). 2-phase dbuf loop (v3).
//   LDS 64KB -> 2 blocks/CU. Grid 512.
// ---------------------------------------------------------------------------
__global__ __launch_bounds__(256, 2)
void attn_fwd(const u16* __restrict__ Q, const u16* __restrict__ Kg,
              const u16* __restrict__ Vt, u16* __restrict__ O)
{
    constexpr int D = 1024, CSTR = 35;
    __shared__ __align__(16) char smem[65536];   // K 32K | V^T 32K (merge buf reuses K)

    const int tid = threadIdx.x, wid = tid >> 6, lane = tid & 63;
    const int grp = wid >> 1, w = wid & 1;
    const int q32 = lane & 31, hf = lane >> 5;
    const int rk = lane & 7;                     // frag-read swizzle key (row&7)

    const int fid = blockIdx.x;
    const int wk = (fid & 7) * 64 + (fid >> 3);
    const int qblk = wk & 15, head = (wk >> 4) & 15, b = wk >> 8;
    const int q0 = qblk * 64 + w * 32;

    // Q fragments (B-operand: col=q32, k = hf*8+e), pre-scaled by 0.125*log2e
    const u16* Qrow = Q + (size_t)(b * 1024 + q0 + q32) * D + head * 64;
    bf16x8 qf[4];
#pragma unroll
    for (int ds = 0; ds < 4; ++ds)
        qf[ds] = *(const bf16x8*)(Qrow + ds * 16 + hf * 8);

    // staging (wave stages rows w*32+c*8+(lane>>3) of its group's tiles)
    const int sr3 = lane >> 3;
    const int scol = ((lane & 7) ^ (sr3 & 7)) * 8;
    const u16* kp = Kg + (size_t)(b * 4096 + grp * 2048 + w * 32 + sr3) * D + head * 64 + scol;
    const u16* vp = Vt + ((size_t)(b * 16 + head) * 64 + w * 32 + sr3) * 4096 + grp * 2048 + scol;

    auto stage = [&](int buf, int kv0) {
        char* kd = smem + buf * 16384 + grp * 8192 + w * 4096;
        char* vd = smem + 32768 + buf * 16384 + grp * 8192 + w * 4096;
#pragma unroll
        for (int c = 0; c < 4; ++c) {
            gload_lds16(kp + (size_t)(kv0 + c * 8) * D,     kd + c * 1024);
            gload_lds16(vp + (size_t)(c * 8) * 4096 + kv0,  vd + c * 1024);
        }
    };

    f32x16 o0, o1;
#pragma unroll
    for (int r = 0; r < 16; ++r) { o0[r] = 0.f; o1[r] = 0.f; }
    float m = -INFINITY, l = 0.f;

    stage(0, 0);
    asm volatile("s_waitcnt vmcnt(0)" ::: "memory");
    asm volatile("s_barrier" ::: "memory");

    for (int t = 0; t < 32; ++t) {
        const int cur = t & 1;
        if (t < 31) stage(cur ^ 1, (t + 1) * 64);

        const u16* kb = (const u16*)(smem + cur * 16384 + grp * 8192);
        const u16* vb = (const u16*)(smem + 32768 + cur * 16384 + grp * 8192);

        // QK^T: S^T[kv][q], two 32-kv macrotiles, d-reduction in 4 steps
        f32x16 s0, s1;
#pragma unroll
        for (int r = 0; r < 16; ++r) { s0[r] = 0.f; s1[r] = 0.f; }
#pragma unroll
        for (int ds = 0; ds < 4; ++ds) {
            bf16x8 kf0 = *(const bf16x8*)&kb[(q32) * 64      + ((ds * 2 + hf) ^ rk) * 8];
            bf16x8 kf1 = *(const bf16x8*)&kb[(32 + q32) * 64 + ((ds * 2 + hf) ^ rk) * 8];
            s0 = MFMA32(kf0, qf[ds], s0);
            s1 = MFMA32(kf1, qf[ds], s1);
        }

        // online softmax, fully per-lane (q = q32); halves combine via xor-32
        float pmax = s0[0];
#pragma unroll
        for (int r = 1; r < 16; ++r) pmax = fmaxf(pmax, s0[r]);
#pragma unroll
        for (int r = 0; r < 16; ++r) pmax = fmaxf(pmax, s1[r]);
        pmax = fmaxf(pmax, __shfl_xor(pmax, 32, 64));
        if (!__all(pmax <= m)) {
            const float mn = fmaxf(m, pmax);
            const float corr = fexp2(m - mn);
            l *= corr;
#pragma unroll
            for (int r = 0; r < 16; ++r) { o0[r] *= corr; o1[r] *= corr; }
            m = mn;
        }
        float lsum = 0.f;
#pragma unroll
        for (int r = 0; r < 16; ++r) { s0[r] = fexp2(s0[r] - m); lsum += s0[r]; }
#pragma unroll
        for (int r = 0; r < 16; ++r) { s1[r] = fexp2(s1[r] - m); lsum += s1[r]; }
        l += lsum;

        // P -> PV B-operand in registers (T12): per (mt,kq):
        //   swap(cvtpk(p[s+0],p[s+1]), cvtpk(p[s+4],p[s+5])) -> words 0,2
        //   swap(cvtpk(p[s+2],p[s+3]), cvtpk(p[s+6],p[s+7])) -> words 1,3
        bf16x8 pa[4];
#pragma unroll
        for (int mt = 0; mt < 2; ++mt) {
#pragma unroll
            for (int kq = 0; kq < 2; ++kq) {
                const int s_ = 8 * kq;
                float e0, e1, e2, e3, e4, e5, e6, e7;
                if (mt == 0) {
                    e0 = s0[s_+0]; e1 = s0[s_+1]; e2 = s0[s_+2]; e3 = s0[s_+3];
                    e4 = s0[s_+4]; e5 = s0[s_+5]; e6 = s0[s_+6]; e7 = s0[s_+7];
                } else {
                    e0 = s1[s_+0]; e1 = s1[s_+1]; e2 = s1[s_+2]; e3 = s1[s_+3];
                    e4 = s1[s_+4]; e5 = s1[s_+5]; e6 = s1[s_+6]; e7 = s1[s_+7];
                }
                unsigned wa = cvt_pk_bf16(e0, e1);
                unsigned wb = cvt_pk_bf16(e4, e5);
                unsigned wc = cvt_pk_bf16(e2, e3);
                unsigned wd = cvt_pk_bf16(e6, e7);
                i32x2 r02 = __builtin_amdgcn_permlane32_swap((int)wa, (int)wb, false, false);
                i32x2 r13 = __builtin_amdgcn_permlane32_swap((int)wc, (int)wd, false, false);
                union { unsigned u[4]; bf16x8 v; } uw;
                uw.u[0] = (unsigned)r02[0];
                uw.u[1] = (unsigned)r13[0];
                uw.u[2] = (unsigned)r02[1];
                uw.u[3] = (unsigned)r13[1];
                pa[mt * 2 + kq] = uw.v;
            }
        }

        // PV: out^T[d][q] += V^T . P^T  (A = V^T frag, B = P frag)
#pragma unroll
        for (int ks = 0; ks < 4; ++ks) {
            bf16x8 vf0 = *(const bf16x8*)&vb[(q32) * 64      + ((ks * 2 + hf) ^ rk) * 8];
            bf16x8 vf1 = *(const bf16x8*)&vb[(32 + q32) * 64 + ((ks * 2 + hf) ^ rk) * 8];
            o0 = MFMA32(vf0, pa[ks], o0);
            o1 = MFMA32(vf1, pa[ks], o1);
        }

        asm volatile("s_waitcnt vmcnt(0)" ::: "memory");
        asm volatile("s_barrier" ::: "memory");
    }

    // full row-sum across lane halves
    l += __shfl_xor(l, 32, 64);

    // merge the two kv groups through LDS (K region dead)
    float* cb = (float*)smem;
    if (grp == 1) {
        float* dst = cb + (size_t)(w * 64 + lane) * CSTR;
        dst[0] = m; dst[1] = l;
#pragma unroll
        for (int r = 0; r < 16; ++r) { dst[2 + r] = o0[r]; dst[18 + r] = o1[r]; }
    }
    __syncthreads();
    if (grp == 0) {
        const float* src = cb + (size_t)(w * 64 + lane) * CSTR;
        const float m1 = src[0], l1 = src[1];
        const float M = fmaxf(m, m1);
        const float c0 = fexp2(m - M), c1 = fexp2(m1 - M);
        const float rl = 1.f / (l * c0 + l1 * c1);
        u16* Orow = O + (size_t)(b * 1024 + q0 + q32) * D + head * 64;
#pragma unroll
        for (int dt = 0; dt < 2; ++dt) {
#pragma unroll
            for (int rq = 0; rq < 4; ++rq) {
                float v0, v1, v2, v3;
                if (dt == 0) {
                    v0 = (o0[rq*4+0] * c0 + src[2 + rq*4+0] * c1) * rl;
                    v1 = (o0[rq*4+1] * c0 + src[2 + rq*4+1] * c1) * rl;
                    v2 = (o0[rq*4+2] * c0 + src[2 + rq*4+2] * c1) * rl;
                    v3 = (o0[rq*4+3] * c0 + src[2 + rq*4+3] * c1) * rl;
                } else {
                    v0 = (o1[rq*4+0] * c0 + src[18 + rq*4+0] * c1) * rl;
                    v1 = (o1[rq*4+1] * c0 + src[18 + rq*4+1] * c1) * rl;
                    v2 = (o1[rq*4+2] * c0 + src[18 + rq*4+2] * c1) * rl;
                    v3 = (o1[rq*4+3] * c0 + src[18 + rq*4+3] * c1) * rl;
                }
                U16x4 pk = { f2bf(v0), f2bf(v1), f2bf(v2), f2bf(v3) };
                *(U16x4*)&Orow[dt * 32 + rq * 8 + hf * 4] = pk;
            }
        }
    }
}

// ---------------------------------------------------------------------------
extern "C" void kernel_launch(void* const* d_in, const int* in_sizes, int n_in,
                              void* d_out, int out_size, void* d_ws, size_t ws_size,
                              hipStream_t stream)
{
    const float* query   = (const float*)d_in[0];
    const float* context = (const float*)d_in[1];
    const float* wq = (const float*)d_in[2];
    const float* bq = (const float*)d_in[3];
    const float* wk = (const float*)d_in[4];
    const float* bk = (const float*)d_in[5];
    const float* wv = (const float*)d_in[6];
    const float* bv = (const float*)d_in[7];
    const float* wo = (const float*)d_in[8];
    const float* bo = (const float*)d_in[9];
    const float* g_q  = (const float*)d_in[10];
    const float* b_q  = (const float*)d_in[11];
    const float* g_kv = (const float*)d_in[12];
    const float* b_kv = (const float*)d_in[13];

    char* p = (char*)d_ws;
    auto alloc = [&](size_t bytes) { char* r = p; p += (bytes + 255) & ~(size_t)255; return r; };
    u16*   wqb  = (u16*)alloc(1024 * 1024 * 2);
    u16*   wkb  = (u16*)alloc(1024 * 1024 * 2);   // wkb+wvb contiguous = Wkv [2048,1024]
    u16*   wvb  = (u16*)alloc(1024 * 1024 * 2);
    u16*   wob  = (u16*)alloc(1024 * 1024 * 2);
    u16*   qnb  = (u16*)alloc((size_t)2048 * 1024 * 2);
    u16*   cnb  = (u16*)alloc((size_t)8192 * 1024 * 2);
    u16*   Qb   = (u16*)alloc((size_t)2048 * 1024 * 2);
    u16*   Kb   = (u16*)alloc((size_t)8192 * 1024 * 2);
    u16*   Vtb  = (u16*)alloc((size_t)8192 * 1024 * 2);
    u16*   AOb  = (u16*)alloc((size_t)2048 * 1024 * 2);

    prep<<<3584, 256, 0, stream>>>(query, context, g_q, b_q, g_kv, b_kv,
                                   qnb, cnb,
                                   (const float4*)wq, (const float4*)wk,
                                   (const float4*)wv, (const float4*)wo,
                                   (U16x4*)wqb, (U16x4*)wkb, (U16x4*)wvb, (U16x4*)wob);

    // Q = (qn.wq^T + bq) * 0.125 * log2(e)  (attn scale + exp2 conversion folded)
    gemm_bt64<0><<<dim3(32, 8), 256, 0, stream>>>(qnb, wqb, bq, nullptr, Qb, 2048, 1024, 1024, 0.18033688f);
    // K row-major + V transposed, one pass over cnb
    gemm_kv8<<<dim3(256), 512, 0, stream>>>(cnb, wkb, bk, bv, Kb, Vtb);

    attn_fwd<<<dim3(512), 256, 0, stream>>>(Qb, Kb, Vtb, AOb);

    // out = qn(bf16) + AO.wo^T + bo   (f32 output, residual fused)
    gemm_bt64<1><<<dim3(32, 8), 256, 0, stream>>>(AOb, wob, bo, qnb, d_out, 2048, 1024, 1024, 1.0f);
}